// Round 5
// baseline (334.535 us; speedup 1.0000x reference)
//
#include <hip/hip_runtime.h>

// imgs (8,3,1024,1024) fp32, z (1e6,2) fp32 -> out (8,2) fp32.
// Counting-sort points into 16x16-pixel bins; one block per bin stages the
// 17x17x24-plane region (27.7 KB) into LDS, then points read 2x2 neighborhoods
// from LDS with immediate offsets. R4 showed the global gather was
// L1-transaction bound (554 GB/s, VALUBusy 7.6%): 64 divergent lanes touched
// ~40+ lines per wave-load. LDS staging collapses that.
// Points stored compressed: u32 pixel index + 2x u16 fixed-point frac (8 B).

#define NYX 1024
#define BATCH 8
#define CH 3
#define NPL (BATCH * CH)               // 24 planes
#define BIN_SHIFT 4                    // 16-pixel bins
#define NBIN_SIDE (NYX >> BIN_SHIFT)   // 64
#define NBINS (NBIN_SIDE * NBIN_SIDE)  // 4096
#define PAD 32                         // u32 stride per bin counter = 128 B line
#define RDIM 17
#define RPL (RDIM * RDIM)              // 289 floats per plane region

// ws layout (bytes):
//   [0]        u32 counts[NBINS*PAD]   (512 KB, line-padded)
//   [524288]   u32 cursors[NBINS*PAD]  (512 KB, line-padded)
//   [1048576]  u32 offsets[NBINS+1]    (16388 B, 32 KB slot)
//   [1081344]  uint2 pts[npts]         (8 MB)
#define WS_COUNTS 0
#define WS_CURS   524288
#define WS_OFFS   1048576
#define WS_PTS    1081344

__device__ __forceinline__ bool point_setup(float zy, float zx,
                                            int& yg, int& xg,
                                            float& fy, float& fx) {
    float x0y = zy * (float)(NYX - 1);
    float x0x = zx * (float)(NYX - 1);
    bool oob = (x0y < 0.0f) || (x0y > (float)(NYX - 1)) ||
               (x0x < 0.0f) || (x0x > (float)(NYX - 1));
    if (oob) return false;
    yg = min((int)floorf(x0y), NYX - 2);
    xg = min((int)floorf(x0x), NYX - 2);
    fy = (float)yg - x0y;   // in (-1, 0]
    fx = (float)xg - x0x;
    return true;
}

__global__ __launch_bounds__(256) void zero_meta_kernel(
    unsigned* __restrict__ counts, float* __restrict__ out)
{
    int t = blockIdx.x * blockDim.x + threadIdx.x;
    if (t < NBINS * PAD) counts[t] = 0u;
    if (t < 16) out[t] = 0.0f;
}

__global__ __launch_bounds__(256) void hist_kernel(
    const float* __restrict__ z, unsigned* __restrict__ counts, int npts)
{
    int p = blockIdx.x * blockDim.x + threadIdx.x;
    if (p >= npts) return;
    float2 zz = ((const float2*)z)[p];
    int yg, xg; float fy, fx;
    if (!point_setup(zz.x, zz.y, yg, xg, fy, fx)) return;
    int bin = ((yg >> BIN_SHIFT) << 6) | (xg >> BIN_SHIFT);
    atomicAdd(&counts[bin * PAD], 1u);
}

// 4096-bin exclusive scan: 1024 threads, 4 bins per thread.
__global__ __launch_bounds__(1024) void scan_kernel(
    const unsigned* __restrict__ counts,
    unsigned* __restrict__ offsets, unsigned* __restrict__ cursors)
{
    __shared__ unsigned tmp[1024];
    int t = threadIdx.x;
    unsigned c0 = counts[(4 * t + 0) * PAD];
    unsigned c1 = counts[(4 * t + 1) * PAD];
    unsigned c2 = counts[(4 * t + 2) * PAD];
    unsigned c3 = counts[(4 * t + 3) * PAD];
    unsigned s0 = c0, s1 = s0 + c1, s2 = s1 + c2, s3 = s2 + c3;
    tmp[t] = s3;
    __syncthreads();
    unsigned v = s3;
#pragma unroll
    for (int off = 1; off < 1024; off <<= 1) {
        unsigned add = (t >= off) ? tmp[t - off] : 0u;
        __syncthreads();
        v += add;
        tmp[t] = v;
        __syncthreads();
    }
    unsigned base = v - s3;   // exclusive base for this thread's 4 bins
    unsigned o0 = base, o1 = base + s0, o2 = base + s1, o3 = base + s2;
    offsets[4 * t + 0] = o0;  cursors[(4 * t + 0) * PAD] = o0;
    offsets[4 * t + 1] = o1;  cursors[(4 * t + 1) * PAD] = o1;
    offsets[4 * t + 2] = o2;  cursors[(4 * t + 2) * PAD] = o2;
    offsets[4 * t + 3] = o3;  cursors[(4 * t + 3) * PAD] = o3;
    if (t == 1023) offsets[NBINS] = v;
}

__global__ __launch_bounds__(256) void scatter_kernel(
    const float* __restrict__ z, unsigned* __restrict__ cursors,
    uint2* __restrict__ pts, int npts)
{
    int p = blockIdx.x * blockDim.x + threadIdx.x;
    if (p >= npts) return;
    float2 zz = ((const float2*)z)[p];
    int yg, xg; float fy, fx;
    if (!point_setup(zz.x, zz.y, yg, xg, fy, fx)) return;
    int bin = ((yg >> BIN_SHIFT) << 6) | (xg >> BIN_SHIFT);
    unsigned pos = atomicAdd(&cursors[bin * PAD], 1u);
    // fx, fy in (-1,0] -> 16-bit fixed point, abs err <= 7.6e-6
    unsigned qfx = (unsigned)(-fx * 65535.0f + 0.5f);
    unsigned qfy = (unsigned)(-fy * 65535.0f + 0.5f);
    uint2 rec;
    rec.x = (unsigned)((yg << 10) | xg);
    rec.y = qfx | (qfy << 16);
    pts[pos] = rec;
}

__global__ __launch_bounds__(256) void gather_bin_kernel(
    const float* __restrict__ imgs, const uint2* __restrict__ pts,
    const unsigned* __restrict__ offsets, float* __restrict__ out)
{
    // bijective XCD-chunk swizzle: each XCD gets a contiguous bin range so
    // neighboring bins (shared edge lines) stay in the same XCD L2.
    unsigned nb = gridDim.x, q = nb >> 3, r = nb & 7;
    unsigned x = blockIdx.x & 7, j = blockIdx.x >> 3;
    unsigned sb = x * q + min(x, r) + j;     // bin id this block owns

    int by = (int)(sb >> 6), bx = (int)(sb & 63);
    int y0 = by << BIN_SHIFT, x0 = bx << BIN_SHIFT;

    __shared__ float reg[NPL * RPL];   // 27744 B
    // stage 17x17 region of all 24 planes (zero-pad outside image)
    for (int i = threadIdx.x; i < NPL * RPL; i += 256) {
        int pl = i / RPL;
        int rem = i - pl * RPL;
        int rr = rem / RDIM;
        int cc = rem - rr * RDIM;
        int gy = y0 + rr, gx = x0 + cc;
        float v = 0.0f;
        if (gy < NYX && gx < NYX)
            v = imgs[(size_t)pl * (NYX * NYX) + (gy << 10) + gx];
        reg[i] = v;
    }
    __syncthreads();

    unsigned lo = offsets[sb], hi = offsets[sb + 1];

    float acc0[BATCH];
    float acc1[BATCH];
#pragma unroll
    for (int b = 0; b < BATCH; ++b) { acc0[b] = 0.0f; acc1[b] = 0.0f; }

    for (unsigned p = lo + threadIdx.x; p < hi; p += 256) {
        uint2 pt = pts[p];
        int yg = (int)(pt.x >> 10), xg = (int)(pt.x & 1023);
        float fx = -(float)(pt.y & 0xffffu) * (1.0f / 65535.0f);
        float fy = -(float)(pt.y >> 16)     * (1.0f / 65535.0f);
        int l = (yg - y0) * RDIM + (xg - x0);
        const float* s = &reg[l];
#pragma unroll
        for (int k = 0; k < NPL; ++k) {
            float g00 = s[k * RPL + 0];
            float g01 = s[k * RPL + 1];
            float g10 = s[k * RPL + RDIM];
            float g11 = s[k * RPL + RDIM + 1];
            float a1 = g10 - g00;
            float a2 = g11 - g01;
            float a3 = g01 - g00;
            float d  = a1 - a2;
            int b = k / CH;
            acc0[b] += d * fx + a1;
            acc1[b] += d * fy + a3;
        }
    }

#pragma unroll
    for (int b = 0; b < BATCH; ++b) {
#pragma unroll
        for (int off = 32; off > 0; off >>= 1) {
            acc0[b] += __shfl_down(acc0[b], off, 64);
            acc1[b] += __shfl_down(acc1[b], off, 64);
        }
    }

    __shared__ float sred[4][16];
    int lane = threadIdx.x & 63;
    int wave = threadIdx.x >> 6;
    if (lane == 0) {
#pragma unroll
        for (int b = 0; b < BATCH; ++b) {
            sred[wave][2 * b + 0] = acc0[b];
            sred[wave][2 * b + 1] = acc1[b];
        }
    }
    __syncthreads();
    if (threadIdx.x < 16) {
        float s = sred[0][threadIdx.x] + sred[1][threadIdx.x] +
                  sred[2][threadIdx.x] + sred[3][threadIdx.x];
        atomicAdd(&out[threadIdx.x], s);
    }
}

// ---- fallback (round-1 unsorted path) if ws is too small ----
__global__ void zero_out_kernel(float* __restrict__ out) {
    int i = threadIdx.x;
    if (i < 16) out[i] = 0.0f;
}

__global__ __launch_bounds__(256) void interp_grad_kernel(
    const float* __restrict__ imgs, const float* __restrict__ z,
    float* __restrict__ out, int npts)
{
    int p = blockIdx.x * blockDim.x + threadIdx.x;
    float acc0[BATCH];
    float acc1[BATCH];
#pragma unroll
    for (int b = 0; b < BATCH; ++b) { acc0[b] = 0.0f; acc1[b] = 0.0f; }
    if (p < npts) {
        float2 zz = ((const float2*)z)[p];
        int yg, xg; float fy, fx;
        if (point_setup(zz.x, zz.y, yg, xg, fy, fx)) {
            const float* base = imgs + (size_t)yg * NYX + xg;
#pragma unroll
            for (int b = 0; b < BATCH; ++b) {
#pragma unroll
                for (int c = 0; c < CH; ++c) {
                    const float* pl = base + (size_t)(b * CH + c) * (size_t)(NYX * NYX);
                    float g00 = pl[0];
                    float g01 = pl[1];
                    float g10 = pl[NYX];
                    float g11 = pl[NYX + 1];
                    float a1 = g10 - g00;
                    float a2 = g11 - g01;
                    float a3 = g01 - g00;
                    float d  = a1 - a2;
                    acc0[b] += d * fx + a1;
                    acc1[b] += d * fy + a3;
                }
            }
        }
    }
#pragma unroll
    for (int b = 0; b < BATCH; ++b) {
#pragma unroll
        for (int off = 32; off > 0; off >>= 1) {
            acc0[b] += __shfl_down(acc0[b], off, 64);
            acc1[b] += __shfl_down(acc1[b], off, 64);
        }
    }
    __shared__ float sred[4][16];
    int lane = threadIdx.x & 63;
    int wave = threadIdx.x >> 6;
    if (lane == 0) {
#pragma unroll
        for (int b = 0; b < BATCH; ++b) {
            sred[wave][2 * b + 0] = acc0[b];
            sred[wave][2 * b + 1] = acc1[b];
        }
    }
    __syncthreads();
    if (threadIdx.x < 16) {
        float s = sred[0][threadIdx.x] + sred[1][threadIdx.x] +
                  sred[2][threadIdx.x] + sred[3][threadIdx.x];
        atomicAdd(&out[threadIdx.x], s);
    }
}

extern "C" void kernel_launch(void* const* d_in, const int* in_sizes, int n_in,
                              void* d_out, int out_size, void* d_ws, size_t ws_size,
                              hipStream_t stream) {
    const float* imgs = (const float*)d_in[0];
    const float* z    = (const float*)d_in[1];
    float* out        = (float*)d_out;
    int npts = in_sizes[1] / 2;

    size_t ws_need = (size_t)WS_PTS + (size_t)npts * sizeof(uint2);
    int blocks = (npts + 255) / 256;

    if (ws_size < ws_need) {
        zero_out_kernel<<<1, 64, 0, stream>>>(out);
        interp_grad_kernel<<<blocks, 256, 0, stream>>>(imgs, z, out, npts);
        return;
    }

    char* ws = (char*)d_ws;
    unsigned* counts  = (unsigned*)(ws + WS_COUNTS);
    unsigned* cursors = (unsigned*)(ws + WS_CURS);
    unsigned* offsets = (unsigned*)(ws + WS_OFFS);
    uint2*    pts     = (uint2*)(ws + WS_PTS);

    zero_meta_kernel<<<(NBINS * PAD + 255) / 256, 256, 0, stream>>>(counts, out);
    hist_kernel<<<blocks, 256, 0, stream>>>(z, counts, npts);
    scan_kernel<<<1, 1024, 0, stream>>>(counts, offsets, cursors);
    scatter_kernel<<<blocks, 256, 0, stream>>>(z, cursors, pts, npts);
    gather_bin_kernel<<<NBINS, 256, 0, stream>>>(imgs, pts, offsets, out);
}